// Round 1
// baseline (49715.372 us; speedup 1.0000x reference)
//
#include <hip/hip_runtime.h>
#include <hip/hip_bf16.h>
#include <math.h>

// HMM forward: alpha_t = (alpha_{t-1} @ A) * B[:, se[t]],  out = -log(sum(alpha_{T-1}))
// N_STATES=2048, N_OBS=8192, T=8192.
//
// Strategy: single persistent kernel, A entirely in VGPRs (16 MiB across
// 32768 threads = 128 f32 regs/thread), one device-wide barrier per step,
// alpha exchanged via LLC with agent-scope (sc0+sc1) atomics.

#define NS    2048
#define NOBS  8192
#define TSEQ  8192
#define NBLK  64
#define NTHR  512
#define OPB   (NS / NBLK)     // 32 outputs per block
#define JPT   128             // j-slice per thread (2048 j / 16 groups)

__global__ void __launch_bounds__(64) init_ws_kernel(unsigned* cnt) {
  if (threadIdx.x == 0) {
    __hip_atomic_store(cnt, 0u, __ATOMIC_RELAXED, __HIP_MEMORY_SCOPE_AGENT);
  }
}

__device__ __forceinline__ void grid_barrier(unsigned* cnt, unsigned target) {
  __syncthreads();  // drains each wave's outstanding vmem (incl. sc1 stores) before s_barrier
  if (threadIdx.x == 0) {
    __threadfence();
    __hip_atomic_fetch_add(cnt, 1u, __ATOMIC_RELEASE, __HIP_MEMORY_SCOPE_AGENT);
    while (__hip_atomic_load(cnt, __ATOMIC_RELAXED, __HIP_MEMORY_SCOPE_AGENT) < target) {
      __builtin_amdgcn_s_sleep(1);
    }
    __threadfence();
  }
  __syncthreads();
}

__global__ void __launch_bounds__(NTHR) hmm_forward_kernel(
    const float* __restrict__ Pi0,
    const float* __restrict__ A,
    const float* __restrict__ B,
    const int*   __restrict__ se,
    float* __restrict__ out,
    unsigned*    cnt,
    float*       alphaG) {
  __shared__ __align__(16) float alpha_sm[NS];
  __shared__ float red[NTHR / 64][OPB];

  const int tid    = threadIdx.x;
  const int blk    = blockIdx.x;
  const int w      = tid >> 6;      // wave 0..7
  const int lane   = tid & 63;
  const int h      = lane >> 5;     // half-wave
  const int o      = lane & 31;     // output slot within block
  const int i_mine = blk * OPB + o;              // output column owned
  const int jbase  = (w * 2 + h) * JPT;          // j-slice base

  // ---- A column-slice into registers: Areg[m] = A[jbase+m][i_mine]
  // (for fixed j, the 32 lanes of a half-wave read 128 contiguous bytes)
  float Areg[JPT];
#pragma unroll
  for (int m = 0; m < JPT; ++m) {
    Areg[m] = A[(size_t)(jbase + m) * NS + i_mine];
  }

  // ---- alpha_0 = Pi0 * B[:, se[0]], computed redundantly by every block
  {
    const int s0 = se[0];
#pragma unroll
    for (int c = 0; c < 4; ++c) {
      const int i = tid * 4 + c;
      alpha_sm[i] = Pi0[i] * B[(size_t)i * NOBS + s0];
    }
  }
  __syncthreads();

  // prefetch emission value for step 1 (only wave 0 lanes <32 need it)
  float bv_next = 0.f;
  if (tid < OPB) {
    bv_next = B[(size_t)i_mine * NOBS + se[1]];
  }

  for (int t = 1; t < TSEQ; ++t) {
    const float bv = bv_next;
    // prefetch next step's emission value; latency hidden under compute+barrier
    if (tid < OPB) {
      const int tn  = (t + 1 < TSEQ) ? (t + 1) : t;
      const int stn = se[tn];
      bv_next = B[(size_t)i_mine * NOBS + stn];
    }

    // dot over this thread's j-slice (alpha from LDS, A from registers)
    float acc = 0.f;
#pragma unroll
    for (int mm = 0; mm < JPT / 4; ++mm) {
      const float4 av = *reinterpret_cast<const float4*>(&alpha_sm[jbase + 4 * mm]);
      acc = fmaf(Areg[4 * mm + 0], av.x, acc);
      acc = fmaf(Areg[4 * mm + 1], av.y, acc);
      acc = fmaf(Areg[4 * mm + 2], av.z, acc);
      acc = fmaf(Areg[4 * mm + 3], av.w, acc);
    }
    // combine the two half-wave j-slices (same output column)
    acc += __shfl_xor(acc, 32);
    if (lane < 32) red[w][o] = acc;
    __syncthreads();

    // wave 0 finishes the 8-wave reduction, applies emission, publishes alpha_t
    if (tid < OPB) {
      float s = 0.f;
#pragma unroll
      for (int ww = 0; ww < NTHR / 64; ++ww) s += red[ww][tid];
      const float aval = s * bv;
      __hip_atomic_store(&alphaG[(t & 1) * NS + i_mine], aval,
                         __ATOMIC_RELAXED, __HIP_MEMORY_SCOPE_AGENT);
    }

    grid_barrier(cnt, (unsigned)t * (unsigned)NBLK);

    // gather the full new alpha into LDS (cache-bypassing agent-scope loads)
    {
      float* src = &alphaG[(t & 1) * NS];
      float4 v;
      v.x = __hip_atomic_load(&src[4 * tid + 0], __ATOMIC_RELAXED, __HIP_MEMORY_SCOPE_AGENT);
      v.y = __hip_atomic_load(&src[4 * tid + 1], __ATOMIC_RELAXED, __HIP_MEMORY_SCOPE_AGENT);
      v.z = __hip_atomic_load(&src[4 * tid + 2], __ATOMIC_RELAXED, __HIP_MEMORY_SCOPE_AGENT);
      v.w = __hip_atomic_load(&src[4 * tid + 3], __ATOMIC_RELAXED, __HIP_MEMORY_SCOPE_AGENT);
      *reinterpret_cast<float4*>(&alpha_sm[4 * tid]) = v;
    }
    __syncthreads();
  }

  // ---- final: -log(sum(alpha_{T-1})), block 0 only (alpha is in its LDS)
  if (blk == 0) {
    float s = 0.f;
#pragma unroll
    for (int c = 0; c < 4; ++c) s += alpha_sm[4 * tid + c];
#pragma unroll
    for (int off = 32; off > 0; off >>= 1) s += __shfl_xor(s, off);
    if (lane == 0) red[w][0] = s;
    __syncthreads();
    if (tid == 0) {
      float S = 0.f;
#pragma unroll
      for (int ww = 0; ww < NTHR / 64; ++ww) S += red[ww][0];
      out[0] = -logf(S);
    }
  }
}

extern "C" void kernel_launch(void* const* d_in, const int* in_sizes, int n_in,
                              void* d_out, int out_size, void* d_ws, size_t ws_size,
                              hipStream_t stream) {
  const float* Pi0 = (const float*)d_in[0];
  const float* A   = (const float*)d_in[1];
  const float* B   = (const float*)d_in[2];
  const int*   se  = (const int*)d_in[3];
  float*       out = (float*)d_out;

  // ws layout: [0..255] barrier counter; [256..] alphaG double buffer (2*NS f32)
  unsigned* cnt    = (unsigned*)d_ws;
  float*    alphaG = (float*)((char*)d_ws + 256);

  init_ws_kernel<<<1, 64, 0, stream>>>(cnt);
  hmm_forward_kernel<<<NBLK, NTHR, 0, stream>>>(Pi0, A, B, se, out, cnt, alphaG);
}

// Round 2
// 25630.887 us; speedup vs baseline: 1.9397x; 1.9397x over previous
//
#include <hip/hip_runtime.h>
#include <hip/hip_bf16.h>
#include <math.h>

// HMM forward: alpha_t = (alpha_{t-1} @ A) * B[:, se[t]],  out = -log(sum(alpha_{T-1}))
// N_STATES=2048, N_OBS=8192, T=8192.
//
// Persistent kernel, A entirely in VGPRs (128 f32/thread, 64 blk x 512 thr),
// one device-wide barrier per step, alpha exchanged via LLC with relaxed
// agent-scope atomics (no threadfence / no L2 writeback per step).

#define NS    2048
#define NOBS  8192
#define TSEQ  8192
#define NBLK  64
#define NTHR  512
#define OPB   (NS / NBLK)     // 32 outputs per block
#define JPT   128             // j-slice per thread (2048 j / 16 slices per block)

__global__ void __launch_bounds__(64) init_ws_kernel(unsigned* cnt) {
  if (threadIdx.x == 0) {
    __hip_atomic_store(cnt, 0u, __ATOMIC_RELAXED, __HIP_MEMORY_SCOPE_AGENT);
  }
}

__global__ void __launch_bounds__(NTHR, 2) hmm_forward_kernel(
    const float* __restrict__ Pi0,
    const float* __restrict__ A,
    const float* __restrict__ B,
    const int*   __restrict__ se,
    float* __restrict__ out,
    unsigned*    cnt,
    float*       alphaG) {
  __shared__ __align__(16) float alpha_sm[NS];
  __shared__ float red[NTHR / 64][OPB];

  const int tid    = threadIdx.x;
  const int blk    = blockIdx.x;
  const int w      = tid >> 6;      // wave 0..7
  const int lane   = tid & 63;
  const int h      = lane >> 5;     // half-wave
  const int o      = lane & 31;     // output slot within block
  const int i_mine = blk * OPB + o;              // output column owned
  const int jbase  = (w * 2 + h) * JPT;          // j-slice base

  // ---- A column-slice into registers: Areg[m] = A[jbase+m][i_mine]
  // (for fixed j, the 32 lanes of a half-wave read 128 contiguous bytes)
  float Areg[JPT];
#pragma unroll
  for (int m = 0; m < JPT; ++m) {
    Areg[m] = A[(size_t)(jbase + m) * NS + i_mine];
  }

  // ---- alpha_0 = Pi0 * B[:, se[0]], computed redundantly by every block
  {
    const int s0 = se[0];
#pragma unroll
    for (int c = 0; c < 4; ++c) {
      const int i = tid * 4 + c;
      alpha_sm[i] = Pi0[i] * B[(size_t)i * NOBS + s0];
    }
  }
  __syncthreads();

  // prefetch emission value for step 1 (only wave 0 lanes <32 need it)
  float bv_next = 0.f;
  if (tid < OPB) {
    bv_next = B[(size_t)i_mine * NOBS + se[1]];
  }

  for (int t = 1; t < TSEQ; ++t) {
    const float bv = bv_next;
    // prefetch next step's emission value; latency hidden under compute+barrier
    if (tid < OPB) {
      const int tn  = (t + 1 < TSEQ) ? (t + 1) : t;
      bv_next = B[(size_t)i_mine * NOBS + se[tn]];
    }

    // dot over this thread's j-slice (alpha broadcast from LDS, A in regs)
    float a0 = 0.f, a1 = 0.f, a2 = 0.f, a3 = 0.f;
#pragma unroll
    for (int mm = 0; mm < JPT / 4; ++mm) {
      const float4 av = *reinterpret_cast<const float4*>(&alpha_sm[jbase + 4 * mm]);
      a0 = fmaf(Areg[4 * mm + 0], av.x, a0);
      a1 = fmaf(Areg[4 * mm + 1], av.y, a1);
      a2 = fmaf(Areg[4 * mm + 2], av.z, a2);
      a3 = fmaf(Areg[4 * mm + 3], av.w, a3);
    }
    float acc = (a0 + a1) + (a2 + a3);
    // combine the two half-wave j-slices (same output column)
    acc += __shfl_xor(acc, 32);
    if (lane < 32) red[w][o] = acc;
    __syncthreads();   // red[][] ready; alpha_sm reads of this step all done

    // wave 0: finish 8-wave reduction, apply emission, publish, arrive, spin
    if (tid < OPB) {
      float s = 0.f;
#pragma unroll
      for (int ww = 0; ww < NTHR / 64; ++ww) s += red[ww][tid];
      const float aval = s * bv;
      __hip_atomic_store(&alphaG[(t & 1) * NS + i_mine], aval,
                         __ATOMIC_RELAXED, __HIP_MEMORY_SCOPE_AGENT);
      // ensure this wave's 32 publish-stores are at the coherence point
      asm volatile("s_waitcnt vmcnt(0)" ::: "memory");
      if (tid == 0) {
        __hip_atomic_fetch_add(cnt, 1u, __ATOMIC_RELAXED, __HIP_MEMORY_SCOPE_AGENT);
        const unsigned target = (unsigned)t * (unsigned)NBLK;
        while (__hip_atomic_load(cnt, __ATOMIC_RELAXED, __HIP_MEMORY_SCOPE_AGENT) < target) {
          __builtin_amdgcn_s_sleep(1);
        }
      }
      asm volatile("" ::: "memory");
    }
    __syncthreads();   // all threads wait for thread 0's spin

    // gather the full new alpha into LDS (LLC-direct agent-scope loads)
    {
      const float* src = &alphaG[(t & 1) * NS];
      float4 v;
      v.x = __hip_atomic_load(&src[4 * tid + 0], __ATOMIC_RELAXED, __HIP_MEMORY_SCOPE_AGENT);
      v.y = __hip_atomic_load(&src[4 * tid + 1], __ATOMIC_RELAXED, __HIP_MEMORY_SCOPE_AGENT);
      v.z = __hip_atomic_load(&src[4 * tid + 2], __ATOMIC_RELAXED, __HIP_MEMORY_SCOPE_AGENT);
      v.w = __hip_atomic_load(&src[4 * tid + 3], __ATOMIC_RELAXED, __HIP_MEMORY_SCOPE_AGENT);
      *reinterpret_cast<float4*>(&alpha_sm[4 * tid]) = v;
    }
    __syncthreads();   // alpha_sm ready for next step's compute
  }

  // ---- final: -log(sum(alpha_{T-1})), block 0 only (alpha is in its LDS)
  if (blk == 0) {
    float s = 0.f;
#pragma unroll
    for (int c = 0; c < 4; ++c) s += alpha_sm[4 * tid + c];
#pragma unroll
    for (int off = 32; off > 0; off >>= 1) s += __shfl_xor(s, off);
    if (lane == 0) red[w][0] = s;
    __syncthreads();
    if (tid == 0) {
      float S = 0.f;
#pragma unroll
      for (int ww = 0; ww < NTHR / 64; ++ww) S += red[ww][0];
      out[0] = -logf(S);
    }
  }
}

extern "C" void kernel_launch(void* const* d_in, const int* in_sizes, int n_in,
                              void* d_out, int out_size, void* d_ws, size_t ws_size,
                              hipStream_t stream) {
  const float* Pi0 = (const float*)d_in[0];
  const float* A   = (const float*)d_in[1];
  const float* B   = (const float*)d_in[2];
  const int*   se  = (const int*)d_in[3];
  float*       out = (float*)d_out;

  // ws layout: [0..255] barrier counter; [256..] alphaG double buffer (2*NS f32)
  unsigned* cnt    = (unsigned*)d_ws;
  float*    alphaG = (float*)((char*)d_ws + 256);

  init_ws_kernel<<<1, 64, 0, stream>>>(cnt);
  hmm_forward_kernel<<<NBLK, NTHR, 0, stream>>>(Pi0, A, B, se, out, cnt, alphaG);
}

// Round 4
// 17848.376 us; speedup vs baseline: 2.7854x; 1.4360x over previous
//
#include <hip/hip_runtime.h>
#include <hip/hip_bf16.h>
#include <math.h>

// HMM forward: alpha_t = (alpha_{t-1} @ A) * B[:, se[t]],  out = -log(sum(alpha_{T-1}))
// N_STATES=2048, N_OBS=8192, T=8192.
//
// Persistent kernel. A lives in 32 named float4 SSA values per thread
// (128 f32 regs, 64 blk x 512 thr = exactly 16 MiB). Per-step sync is
// tagged dataflow: alpha elements are published as u64 {tag:32 | f32:32}
// via relaxed agent-scope atomics; each reader wave polls the 8 source
// slices it gathers. No counter, no fences, no vmcnt stalls.

#define NS    2048
#define NOBS  8192
#define TSEQ  8192
#define NBLK  64
#define NTHR  512
#define OPB   32              // output columns per block
#define JPT   128             // j-slice length per thread

typedef unsigned long long u64;
typedef unsigned int u32;

// X-macro over the 32 float4 A-fragments
#define A_LIST(X) \
  X(0)  X(1)  X(2)  X(3)  X(4)  X(5)  X(6)  X(7)  \
  X(8)  X(9)  X(10) X(11) X(12) X(13) X(14) X(15) \
  X(16) X(17) X(18) X(19) X(20) X(21) X(22) X(23) \
  X(24) X(25) X(26) X(27) X(28) X(29) X(30) X(31)

__global__ void __launch_bounds__(256) init_ws_kernel(u64* aG) {
  const int i = blockIdx.x * 256 + threadIdx.x;   // 4 blocks -> 1024 threads x 4 = 4096
#pragma unroll
  for (int c = 0; c < 4; ++c) {
    __hip_atomic_store(&aG[i * 4 + c], 0ull, __ATOMIC_RELAXED, __HIP_MEMORY_SCOPE_AGENT);
  }
}

__global__ void __launch_bounds__(NTHR, 2) hmm_forward_kernel(
    const float* __restrict__ Pi0,
    const float* __restrict__ A,
    const float* __restrict__ B,
    const int*   __restrict__ se,
    float* __restrict__ out,
    u64*   __restrict__ aG) {          // [2][NS] tagged alpha
  __shared__ __align__(16) float alpha_sm[NS];
  __shared__ float red[NTHR / 64][OPB];

  const int tid    = threadIdx.x;
  const int blk    = blockIdx.x;
  const int w      = tid >> 6;       // wave 0..7
  const int lane   = tid & 63;
  const int h      = lane >> 5;      // half-wave
  const int o      = lane & 31;      // output slot within block
  const int i_mine = blk * OPB + o;  // owned output column
  const int jbase  = (w * 2 + h) * JPT;

  // ---- A column-slice into 32 named float4 SSA registers:
  //      Ar{k} = A[jbase+4k .. jbase+4k+3][i_mine]
#define DECLA(k) float4 Ar##k;
  A_LIST(DECLA)
#define LOADA(k) { const float* ap = A + (size_t)(jbase + 4 * k) * NS + i_mine; \
                   Ar##k.x = ap[0]; Ar##k.y = ap[NS]; Ar##k.z = ap[2 * NS]; Ar##k.w = ap[3 * NS]; }
  A_LIST(LOADA)

  // ---- alpha_0 = Pi0 * B[:, se[0]], computed redundantly by every block
  {
    const int s0 = se[0];
#pragma unroll
    for (int c = 0; c < 4; ++c) {
      const int i = tid * 4 + c;
      alpha_sm[i] = Pi0[i] * B[(size_t)i * NOBS + s0];
    }
  }
  __syncthreads();

  // emission prefetch for step 1 (only lanes that publish need it: tid<32)
  float bv_next = 0.f;
  if (tid < OPB) bv_next = B[(size_t)i_mine * NOBS + se[1]];

  for (int t = 1; t < TSEQ; ++t) {
    const float bv  = bv_next;
    const int   buf = t & 1;
    if (tid < OPB) {
      const int tn = (t + 1 < TSEQ) ? (t + 1) : t;
      bv_next = B[(size_t)i_mine * NOBS + se[tn]];
    }

    // ---- dot over this thread's 128-long j-slice (alpha from LDS, A in regs)
    float a0 = 0.f, a1 = 0.f, a2 = 0.f, a3 = 0.f;
#define DOT(k) { const float4 av = *reinterpret_cast<const float4*>(&alpha_sm[jbase + 4 * k]); \
                 a0 = fmaf(Ar##k.x, av.x, a0); a1 = fmaf(Ar##k.y, av.y, a1); \
                 a2 = fmaf(Ar##k.z, av.z, a2); a3 = fmaf(Ar##k.w, av.w, a3); }
    A_LIST(DOT)
    float acc = (a0 + a1) + (a2 + a3);
    acc += __shfl_xor(acc, 32);        // combine the two half-wave j-slices
    if (lane < 32) red[w][o] = acc;
    __syncthreads();                    // red ready; alpha_sm reads of this step done

    // ---- wave 0: finish reduction, apply emission, publish tagged alpha_t
    if (w == 0) {
      float s = 0.f;
#pragma unroll
      for (int ww = 0; ww < NTHR / 64; ++ww) s += red[ww][o];
      if (lane < 32) {
        const float aval = s * bv;
        const u64 pkt = (u64)__float_as_uint(aval) | ((u64)(u32)t << 32);
        __hip_atomic_store(&aG[(size_t)buf * NS + blk * OPB + o], pkt,
                           __ATOMIC_RELAXED, __HIP_MEMORY_SCOPE_AGENT);
      }
    }

    // ---- every wave gathers its 8 source-block slices (256 floats) by tag-poll
    {
      const u64* src = aG + (size_t)buf * NS + w * 256 + lane * 4;
      u64 q0, q1, q2, q3;
      const u32 tag = (u32)t;
      for (;;) {
        q0 = __hip_atomic_load(&src[0], __ATOMIC_RELAXED, __HIP_MEMORY_SCOPE_AGENT);
        q1 = __hip_atomic_load(&src[1], __ATOMIC_RELAXED, __HIP_MEMORY_SCOPE_AGENT);
        q2 = __hip_atomic_load(&src[2], __ATOMIC_RELAXED, __HIP_MEMORY_SCOPE_AGENT);
        q3 = __hip_atomic_load(&src[3], __ATOMIC_RELAXED, __HIP_MEMORY_SCOPE_AGENT);
        if ((u32)(q0 >> 32) == tag && (u32)(q1 >> 32) == tag &&
            (u32)(q2 >> 32) == tag && (u32)(q3 >> 32) == tag) break;
      }
      float4 v;
      v.x = __uint_as_float((u32)q0);
      v.y = __uint_as_float((u32)q1);
      v.z = __uint_as_float((u32)q2);
      v.w = __uint_as_float((u32)q3);
      *reinterpret_cast<float4*>(&alpha_sm[w * 256 + lane * 4]) = v;
    }
    __syncthreads();                    // alpha_sm fully updated for next step
  }

  // ---- final: -log(sum(alpha_{T-1})), block 0 only (alpha is in its LDS)
  if (blk == 0) {
    float s = 0.f;
#pragma unroll
    for (int c = 0; c < 4; ++c) s += alpha_sm[4 * tid + c];
#pragma unroll
    for (int off = 32; off > 0; off >>= 1) s += __shfl_xor(s, off);
    if (lane == 0) red[w][0] = s;
    __syncthreads();
    if (tid == 0) {
      float S = 0.f;
#pragma unroll
      for (int ww = 0; ww < NTHR / 64; ++ww) S += red[ww][0];
      out[0] = -logf(S);
    }
  }
}

extern "C" void kernel_launch(void* const* d_in, const int* in_sizes, int n_in,
                              void* d_out, int out_size, void* d_ws, size_t ws_size,
                              hipStream_t stream) {
  const float* Pi0 = (const float*)d_in[0];
  const float* A   = (const float*)d_in[1];
  const float* B   = (const float*)d_in[2];
  const int*   se  = (const int*)d_in[3];
  float*       out = (float*)d_out;

  // ws layout: aG = u64[2][NS] tagged alpha double buffer (32 KiB) at offset 0
  u64* aG = (u64*)d_ws;

  init_ws_kernel<<<4, 256, 0, stream>>>(aG);                 // zero all tags
  hmm_forward_kernel<<<NBLK, NTHR, 0, stream>>>(Pi0, A, B, se, out, aG);
}

// Round 5
// 17465.726 us; speedup vs baseline: 2.8465x; 1.0219x over previous
//
#include <hip/hip_runtime.h>
#include <hip/hip_bf16.h>
#include <math.h>

// HMM forward: alpha_t = (alpha_{t-1} @ A) * B[:, se[t]],  out = -log(sum(alpha_{T-1}))
// N_STATES=2048, N_OBS=8192, T=8192.
//
// Persistent kernel. A lives in 128 f32 regs/thread (64 blk x 512 thr =
// 16 MiB), pinned via opaque empty-asm so the allocator cannot refold the
// loads into the loop. Per-step sync is tagged dataflow (u64 {tag|f32}
// agent-scope atomics). ONE __syncthreads per step: the gather->dot
// dependency is wave-local (each wave gathers exactly its own j-slice);
// the intra-block reduction buffer is parity-double-buffered.

#define NS    2048
#define NOBS  8192
#define TSEQ  8192
#define NBLK  64
#define NTHR  512
#define OPB   32              // output columns per block
#define JPT   128             // j-slice length per thread

typedef unsigned long long u64;
typedef unsigned int u32;

// X-macro over the 32 float4 A-fragments
#define A_LIST(X) \
  X(0)  X(1)  X(2)  X(3)  X(4)  X(5)  X(6)  X(7)  \
  X(8)  X(9)  X(10) X(11) X(12) X(13) X(14) X(15) \
  X(16) X(17) X(18) X(19) X(20) X(21) X(22) X(23) \
  X(24) X(25) X(26) X(27) X(28) X(29) X(30) X(31)

__global__ void __launch_bounds__(256) init_ws_kernel(u64* aG) {
  const int i = blockIdx.x * 256 + threadIdx.x;   // 4 blocks x 256 thr x 4 = 4096
#pragma unroll
  for (int c = 0; c < 4; ++c) {
    __hip_atomic_store(&aG[i * 4 + c], 0ull, __ATOMIC_RELAXED, __HIP_MEMORY_SCOPE_AGENT);
  }
}

__global__ void __launch_bounds__(NTHR, 2) hmm_forward_kernel(
    const float* __restrict__ Pi0,
    const float* __restrict__ A,
    const float* __restrict__ B,
    const int*   __restrict__ se,
    float* __restrict__ out,
    u64*   __restrict__ aG) {          // [2][NS] tagged alpha
  __shared__ __align__(16) float alpha_sm[NS];
  __shared__ float red[2][NTHR / 64][OPB];   // parity double-buffered partials

  const int tid    = threadIdx.x;
  const int blk    = blockIdx.x;
  const int w      = tid >> 6;       // wave 0..7
  const int lane   = tid & 63;
  const int h      = lane >> 5;      // half-wave
  const int o      = lane & 31;      // output slot within block
  const int i_mine = blk * OPB + o;  // owned output column
  const int jbase  = (w * 2 + h) * JPT;

  // ---- A column-slice into 32 named float4 SSA registers:
  //      Ar{k} = A[jbase+4k .. jbase+4k+3][i_mine]
#define DECLA(k) float4 Ar##k;
  A_LIST(DECLA)
#define LOADA(k) { const float* ap = A + (size_t)(jbase + 4 * k) * NS + i_mine; \
                   Ar##k.x = ap[0]; Ar##k.y = ap[NS]; Ar##k.z = ap[2 * NS]; Ar##k.w = ap[3 * NS]; }
  A_LIST(LOADA)
  // Opaque pin: asm-defined scalars cannot be refolded/remat'd into the loop.
#define PIN4(k) asm volatile("" : "+v"(Ar##k.x), "+v"(Ar##k.y), "+v"(Ar##k.z), "+v"(Ar##k.w));
  A_LIST(PIN4)

  // ---- alpha_0 = Pi0 * B[:, se[0]], computed redundantly by every block
  {
    const int s0 = se[0];
#pragma unroll
    for (int c = 0; c < 4; ++c) {
      const int i = tid * 4 + c;
      alpha_sm[i] = Pi0[i] * B[(size_t)i * NOBS + s0];
    }
  }
  __syncthreads();

  // emission prefetch for step 1 (only publishing lanes need it: tid<32)
  float bv_next = 0.f;
  if (tid < OPB) bv_next = B[(size_t)i_mine * NOBS + se[1]];

  for (int t = 1; t < TSEQ; ++t) {
    const float bv  = bv_next;
    const int   buf = t & 1;
    if (tid < OPB) {
      const int tn = (t + 1 < TSEQ) ? (t + 1) : t;
      bv_next = B[(size_t)i_mine * NOBS + se[tn]];
    }

    // ---- dot over this thread's 128-long j-slice (alpha from LDS, A in regs)
    float a0 = 0.f, a1 = 0.f, a2 = 0.f, a3 = 0.f;
#define DOT(k) { const float4 av = *reinterpret_cast<const float4*>(&alpha_sm[jbase + 4 * k]); \
                 a0 = fmaf(Ar##k.x, av.x, a0); a1 = fmaf(Ar##k.y, av.y, a1); \
                 a2 = fmaf(Ar##k.z, av.z, a2); a3 = fmaf(Ar##k.w, av.w, a3); }
    A_LIST(DOT)
    float acc = (a0 + a1) + (a2 + a3);
    acc += __shfl_xor(acc, 32);        // combine the two half-wave j-slices
    if (lane < 32) red[buf][w][o] = acc;
    __syncthreads();   // the ONE barrier per step: red[buf] handoff to wave 0

    // ---- wave 0: finish reduction, apply emission, publish tagged alpha_t
    if (w == 0) {
      float s = 0.f;
#pragma unroll
      for (int ww = 0; ww < NTHR / 64; ++ww) s += red[buf][ww][o];
      if (lane < 32) {
        const float aval = s * bv;
        const u64 pkt = (u64)__float_as_uint(aval) | ((u64)(u32)t << 32);
        __hip_atomic_store(&aG[(size_t)buf * NS + blk * OPB + o], pkt,
                           __ATOMIC_RELAXED, __HIP_MEMORY_SCOPE_AGENT);
      }
    }

    // ---- each wave gathers ITS OWN 256-float j-slice by tag-poll
    // (written region alpha_sm[w*256 .. w*256+255] == read region [jbase, jbase+256):
    //  wave-local dependency, no block barrier needed)
    {
      const u64* src = aG + (size_t)buf * NS + w * 256 + lane * 4;
      u64 q0, q1, q2, q3;
      const u32 tag = (u32)t;
      for (;;) {
        q0 = __hip_atomic_load(&src[0], __ATOMIC_RELAXED, __HIP_MEMORY_SCOPE_AGENT);
        q1 = __hip_atomic_load(&src[1], __ATOMIC_RELAXED, __HIP_MEMORY_SCOPE_AGENT);
        q2 = __hip_atomic_load(&src[2], __ATOMIC_RELAXED, __HIP_MEMORY_SCOPE_AGENT);
        q3 = __hip_atomic_load(&src[3], __ATOMIC_RELAXED, __HIP_MEMORY_SCOPE_AGENT);
        if ((u32)(q0 >> 32) == tag && (u32)(q1 >> 32) == tag &&
            (u32)(q2 >> 32) == tag && (u32)(q3 >> 32) == tag) break;
      }
      float4 v;
      v.x = __uint_as_float((u32)q0);
      v.y = __uint_as_float((u32)q1);
      v.z = __uint_as_float((u32)q2);
      v.w = __uint_as_float((u32)q3);
      *reinterpret_cast<float4*>(&alpha_sm[w * 256 + lane * 4]) = v;
    }
    // no barrier: next dot reads only this wave's own slice
  }

  // ---- final: -log(sum(alpha_{T-1})), block 0 only
  if (blk == 0) {
    __syncthreads();   // all waves' final gathers into alpha_sm
    float s = 0.f;
#pragma unroll
    for (int c = 0; c < 4; ++c) s += alpha_sm[4 * tid + c];
#pragma unroll
    for (int off = 32; off > 0; off >>= 1) s += __shfl_xor(s, off);
    if (lane == 0) red[0][w][0] = s;
    __syncthreads();
    if (tid == 0) {
      float S = 0.f;
#pragma unroll
      for (int ww = 0; ww < NTHR / 64; ++ww) S += red[0][ww][0];
      out[0] = -logf(S);
    }
  }
}

extern "C" void kernel_launch(void* const* d_in, const int* in_sizes, int n_in,
                              void* d_out, int out_size, void* d_ws, size_t ws_size,
                              hipStream_t stream) {
  const float* Pi0 = (const float*)d_in[0];
  const float* A   = (const float*)d_in[1];
  const float* B   = (const float*)d_in[2];
  const int*   se  = (const int*)d_in[3];
  float*       out = (float*)d_out;

  // ws layout: aG = u64[2][NS] tagged alpha double buffer (32 KiB) at offset 0
  u64* aG = (u64*)d_ws;

  init_ws_kernel<<<4, 256, 0, stream>>>(aG);                 // zero all tags
  hmm_forward_kernel<<<NBLK, NTHR, 0, stream>>>(Pi0, A, B, se, out, aG);
}